// Round 1
// baseline (161.655 us; speedup 1.0000x reference)
//
#include <hip/hip_runtime.h>
#include <cstdint>
#include <cstddef>

#define L_SEQ 2048
#define E_DIM 512
#define B_SZ 2
#define WIN 64
#define SCALE_QK 0.044194173824159216f  // 1/sqrt(512)

typedef __attribute__((ext_vector_type(8))) short short8;
typedef __attribute__((ext_vector_type(4))) float floatx4;

__device__ __forceinline__ unsigned short f2bf(float f) {
    unsigned int u = __float_as_uint(f);
    u += 0x7FFFu + ((u >> 16) & 1u);
    return (unsigned short)(u >> 16);
}

// ---------------- fp32 -> bf16 conversion of x, Wq, Wk, Wv ----------------
__global__ __launch_bounds__(256) void cvt_kernel(
    const float* __restrict__ x, const float* __restrict__ wq,
    const float* __restrict__ wk, const float* __restrict__ wv,
    unsigned short* __restrict__ xb, unsigned short* __restrict__ wb)
{
    long i = (long)blockIdx.x * 256 + threadIdx.x;   // 0 .. 720895
    const float* src;
    unsigned short* dst;
    long off;
    if (i < 524288) {
        src = x; dst = xb; off = i;
    } else {
        long j = i - 524288;
        int w = (int)(j >> 16);
        off = j & 65535;
        src = (w == 0) ? wq : ((w == 1) ? wk : wv);
        dst = wb + (long)w * 262144;
    }
    float4 f = ((const float4*)src)[off];
    ushort4 o;
    o.x = f2bf(f.x); o.y = f2bf(f.y); o.z = f2bf(f.z); o.w = f2bf(f.w);
    ((ushort4*)dst)[off] = o;
}

// ---------------- QKV projection: 64x64 tile, BK=64, reg double-buffer (R5 winner) ----------------
// C[m,n] = sum_k X[m,k] W[n,k] + bias[n].  Outputs bf16, coalesced via LDS transpose.
// z==0 -> q[m][n], z==1 -> k[m][n], z==2 -> vT[n][m] (token-contiguous rows).
// grid (64,8,3) = 1536 blocks = 6 blocks/CU.
#define ALD 72   // LDS row stride (bf16): 36 dw -> 2-way conflicts only per 16-lane phase
__global__ __launch_bounds__(256) void qkv_gemm(
    const unsigned short* __restrict__ xb,   // 4096 x 512
    const unsigned short* __restrict__ wb,   // 3 x (512 x 512), (N,K)
    const float* __restrict__ bq, const float* __restrict__ bk, const float* __restrict__ bv,
    unsigned short* __restrict__ q, unsigned short* __restrict__ k,
    unsigned short* __restrict__ vt)
{
    __shared__ __align__(16) unsigned short As[64 * ALD];   // 9216 B (aliased by epilogue)
    __shared__ __align__(16) unsigned short Bs[64 * ALD];

    const int t = threadIdx.x;
    const int w = t >> 6, l = t & 63;
    const int m0 = blockIdx.x * 64, n0 = blockIdx.y * 64, z = blockIdx.z;
    const unsigned short* W = wb + (size_t)z * 262144;
    const float* bias = (z == 0) ? bq : ((z == 1) ? bk : bv);

    floatx4 acc[2][2] = {};
    const int wm = (w >> 1) * 32, wn = (w & 1) * 32;
    const int fr = l & 15, fq = l >> 4, fk = fq * 8;

    const int srow = t >> 2, scol = (t & 3) * 16;
    const unsigned short* gA = xb + (size_t)(m0 + srow) * 512 + scol;
    const unsigned short* gB = W  + (size_t)(n0 + srow) * 512 + scol;

    uint4 ra0 = *(const uint4*)(gA);     uint4 ra1 = *(const uint4*)(gA + 8);
    uint4 rb0 = *(const uint4*)(gB);     uint4 rb1 = *(const uint4*)(gB + 8);

    for (int it = 0; it < 8; it++) {
        *(uint4*)&As[srow * ALD + scol]     = ra0;
        *(uint4*)&As[srow * ALD + scol + 8] = ra1;
        *(uint4*)&Bs[srow * ALD + scol]     = rb0;
        *(uint4*)&Bs[srow * ALD + scol + 8] = rb1;
        __syncthreads();
        if (it < 7) {                       // prefetch next K-slice; overlaps compute below
            int kk = (it + 1) * 64;
            ra0 = *(const uint4*)(gA + kk); ra1 = *(const uint4*)(gA + kk + 8);
            rb0 = *(const uint4*)(gB + kk); rb1 = *(const uint4*)(gB + kk + 8);
        }
        short8 a[2][2], bf[2][2];
#pragma unroll
        for (int i = 0; i < 2; i++)
#pragma unroll
            for (int kh = 0; kh < 2; kh++)
                a[i][kh] = *(const short8*)&As[(wm + i * 16 + fr) * ALD + kh * 32 + fk];
#pragma unroll
        for (int j = 0; j < 2; j++)
#pragma unroll
            for (int kh = 0; kh < 2; kh++)
                bf[j][kh] = *(const short8*)&Bs[(wn + j * 16 + fr) * ALD + kh * 32 + fk];
#pragma unroll
        for (int kh = 0; kh < 2; kh++)
#pragma unroll
            for (int i = 0; i < 2; i++)
#pragma unroll
                for (int j = 0; j < 2; j++)
                    acc[i][j] = __builtin_amdgcn_mfma_f32_16x16x32_bf16(a[i][kh], bf[j][kh], acc[i][j], 0, 0, 0);
        __syncthreads();
    }

    // epilogue: frags (C/D: col=lane&15, row=(lane>>4)*4+reg) -> LDS tile -> coalesced stores
    unsigned short* Tl = As;   // 64 x ALD alias
    float bv_[2];
#pragma unroll
    for (int j = 0; j < 2; j++) bv_[j] = bias[n0 + wn + j * 16 + fr];

    if (z < 2) {
#pragma unroll
        for (int i = 0; i < 2; i++)
#pragma unroll
            for (int j = 0; j < 2; j++)
#pragma unroll
                for (int r = 0; r < 4; r++)
                    Tl[(wm + i * 16 + fq * 4 + r) * ALD + wn + j * 16 + fr] =
                        f2bf(acc[i][j][r] + bv_[j]);
    } else {
#pragma unroll
        for (int i = 0; i < 2; i++)
#pragma unroll
            for (int j = 0; j < 2; j++)
#pragma unroll
                for (int r = 0; r < 4; r++)
                    Tl[(wn + j * 16 + fr) * ALD + wm + i * 16 + fq * 4 + r] =
                        f2bf(acc[i][j][r] + bv_[j]);
    }
    __syncthreads();

    const int tr = t >> 2, tc = (t & 3) * 16;
    uint4 v0 = *(const uint4*)&Tl[tr * ALD + tc];
    uint4 v1 = *(const uint4*)&Tl[tr * ALD + tc + 8];
    if (z < 2) {
        unsigned short* out = (z == 0) ? q : k;
        *(uint4*)&out[(size_t)(m0 + tr) * 512 + n0 + tc]     = v0;
        *(uint4*)&out[(size_t)(m0 + tr) * 512 + n0 + tc + 8] = v1;
    } else {
        *(uint4*)&vt[(size_t)(n0 + tr) * 4096 + m0 + tc]     = v0;
        *(uint4*)&vt[(size_t)(n0 + tr) * 4096 + m0 + tc + 8] = v1;
    }
}

// ---------------- fused attention: scores + softmax + PV, one wave per 16-row Q-tile --------
// grid (128 Qtiles, 2 b), 64 threads. S lives only in a 16x164 fp32 LDS tile
// (transposed through LDS because MFMA C-layout spreads a q-row across lanes).
// Softmax computed exactly ONCE per q-row (was 8x in the split pv kernel);
// S never touches global memory.  256 blocks = 1 wave/CU, zero inter-wave sync.
#define SLD 164   // LDS row stride (fp32): 164%32=4 -> 2-way conflicts max on row reads
__global__ __launch_bounds__(64) void attn_fused(
    const unsigned short* __restrict__ qb, const unsigned short* __restrict__ kb,
    const unsigned short* __restrict__ vt, float* __restrict__ out)
{
    __shared__ __align__(16) float Sl[16 * SLD];   // 10.5 KB

    const int l = threadIdx.x;
    const int fr = l & 15, fq = l >> 4;
    const int Q0 = blockIdx.x * 16;
    const int b  = blockIdx.y;
    const int R0 = Q0 - WIN;

    // ---- Q fragments: row Q0+fr, cols fq*8 + ks*32 (A-frag layout, reused for all 9 ntiles)
    const unsigned short* qrow = qb + (size_t)(b * L_SEQ + Q0 + fr) * 512 + fq * 8;
    short8 qf[16];
#pragma unroll
    for (int ks = 0; ks < 16; ks++) qf[ks] = *(const short8*)(qrow + ks * 32);

    // ---- scores: 9 n-tiles of 16 keys each -> masked/scaled into Sl
#pragma unroll
    for (int nt = 0; nt < 9; nt++) {
        const int tok = R0 + nt * 16 + fr;
        const bool kvalid = (tok >= 0) && (tok < L_SEQ);
        const unsigned short* krow = kb + (size_t)(b * L_SEQ) * 512 + (size_t)tok * 512 + fq * 8;

        floatx4 acc = {};
#pragma unroll
        for (int ks = 0; ks < 16; ks++) {
            short8 bfr = {};
            if (kvalid) bfr = *(const short8*)(krow + ks * 32);
            acc = __builtin_amdgcn_mfma_f32_16x16x32_bf16(qf[ks], bfr, acc, 0, 0, 0);
        }
        const int jg = nt * 16 + fr;
#pragma unroll
        for (int r = 0; r < 4; r++) {
            int qq = fq * 4 + r;    // C/D layout: col=lane&15, row=(lane>>4)*4+r
            bool valid = kvalid && (jg >= qq) && (jg <= qq + 128);
            Sl[qq * SLD + jg] = valid ? acc[r] * SCALE_QK : -1e30f;
        }
    }
    __syncthreads();   // single wave: cheap; orders ds_write -> ds_read

    // ---- softmax, once per q-row: lane covers row fr, cols fq*8 + ks*32 + j
    const float* Srow = &Sl[fr * SLD + fq * 8];
    float sv[5][8];
#pragma unroll
    for (int ks = 0; ks < 5; ks++) {
        float4 u0 = *(const float4*)(Srow + ks * 32);
        float4 u1 = *(const float4*)(Srow + ks * 32 + 4);
        sv[ks][0] = u0.x; sv[ks][1] = u0.y; sv[ks][2] = u0.z; sv[ks][3] = u0.w;
        sv[ks][4] = u1.x; sv[ks][5] = u1.y; sv[ks][6] = u1.z; sv[ks][7] = u1.w;
    }
    if (fq >= 2) {                    // cols 144..159: unwritten pad
#pragma unroll
        for (int j = 0; j < 8; j++) sv[4][j] = -1e30f;
    }
    float m = -1e30f;
#pragma unroll
    for (int ks = 0; ks < 5; ks++)
#pragma unroll
        for (int j = 0; j < 8; j++) m = fmaxf(m, sv[ks][j]);
    m = fmaxf(m, __shfl_xor(m, 16));
    m = fmaxf(m, __shfl_xor(m, 32));
    float sum = 0.f;
#pragma unroll
    for (int ks = 0; ks < 5; ks++)
#pragma unroll
        for (int j = 0; j < 8; j++) { float e = __expf(sv[ks][j] - m); sv[ks][j] = e; sum += e; }
    sum += __shfl_xor(sum, 16);
    sum += __shfl_xor(sum, 32);
    float inv = 1.f / sum;

    short8 a[5];
#pragma unroll
    for (int ks = 0; ks < 5; ks++)
#pragma unroll
        for (int j = 0; j < 8; j++) a[ks][j] = (short)f2bf(sv[ks][j] * inv);

    // ---- PV over the full 512 output cols, in 4 groups of 128 (bounds VGPRs to oa[8])
    float* op = out + (size_t)b * L_SEQ * E_DIM;
#pragma unroll
    for (int eg = 0; eg < 4; eg++) {
        floatx4 oa[8] = {};
#pragma unroll
        for (int ks = 0; ks < 5; ks++) {
            int tok0 = R0 + ks * 32 + fq * 8;              // mod-8 aligned granule
            bool tv = (tok0 >= 0) && (tok0 < L_SEQ);
#pragma unroll
            for (int e8 = 0; e8 < 8; e8++) {
                short8 bfr = {};
                if (tv) bfr = *(const short8*)&vt[(size_t)(eg * 128 + e8 * 16 + fr) * 4096 + b * L_SEQ + tok0];
                oa[e8] = __builtin_amdgcn_mfma_f32_16x16x32_bf16(a[ks], bfr, oa[e8], 0, 0, 0);
            }
        }
#pragma unroll
        for (int e8 = 0; e8 < 8; e8++)
#pragma unroll
            for (int r = 0; r < 4; r++)
                op[(size_t)(Q0 + fq * 4 + r) * 512 + eg * 128 + e8 * 16 + fr] = oa[e8][r];
    }
}

// ---------------- launch ----------------
extern "C" void kernel_launch(void* const* d_in, const int* in_sizes, int n_in,
                              void* d_out, int out_size, void* d_ws, size_t ws_size,
                              hipStream_t stream)
{
    const float* x  = (const float*)d_in[0];
    const float* Wq = (const float*)d_in[1];
    const float* bq = (const float*)d_in[2];
    const float* Wk = (const float*)d_in[3];
    const float* bk = (const float*)d_in[4];
    const float* Wv = (const float*)d_in[5];
    const float* bv = (const float*)d_in[6];
    float* out = (float*)d_out;

    char* ws = (char*)d_ws;
    unsigned short* qb = (unsigned short*)(ws);                  // 4 MB bf16 q
    unsigned short* kb = (unsigned short*)(ws + 4194304);        // 4 MB bf16 k
    unsigned short* vt = (unsigned short*)(ws + 8388608);        // 4 MB bf16 v^T [e][tok]
    unsigned short* xb = (unsigned short*)(ws + 12582912);       // 4 MB bf16 x
    unsigned short* wb = (unsigned short*)(ws + 16777216);       // 1.5 MB bf16 W

    cvt_kernel<<<2816, 256, 0, stream>>>(x, Wq, Wk, Wv, xb, wb);
    qkv_gemm<<<dim3(64, 8, 3), 256, 0, stream>>>(xb, wb, bq, bk, bv, qb, kb, vt);
    attn_fused<<<dim3(128, 2), 64, 0, stream>>>(qb, kb, vt, out);
}

// Round 2
// 112.547 us; speedup vs baseline: 1.4363x; 1.4363x over previous
//
#include <hip/hip_runtime.h>
#include <cstdint>
#include <cstddef>

#define L_SEQ 2048
#define E_DIM 512
#define B_SZ 2
#define WIN 64
#define SCALE_QK 0.044194173824159216f  // 1/sqrt(512)

typedef __attribute__((ext_vector_type(8))) short short8;
typedef __attribute__((ext_vector_type(4))) float floatx4;

__device__ __forceinline__ unsigned short f2bf(float f) {
    unsigned int u = __float_as_uint(f);
    u += 0x7FFFu + ((u >> 16) & 1u);
    return (unsigned short)(u >> 16);
}

// ---------------- fp32 -> bf16 conversion of x, Wq, Wk, Wv ----------------
__global__ __launch_bounds__(256) void cvt_kernel(
    const float* __restrict__ x, const float* __restrict__ wq,
    const float* __restrict__ wk, const float* __restrict__ wv,
    unsigned short* __restrict__ xb, unsigned short* __restrict__ wb)
{
    long i = (long)blockIdx.x * 256 + threadIdx.x;   // 0 .. 720895
    const float* src;
    unsigned short* dst;
    long off;
    if (i < 524288) {
        src = x; dst = xb; off = i;
    } else {
        long j = i - 524288;
        int w = (int)(j >> 16);
        off = j & 65535;
        src = (w == 0) ? wq : ((w == 1) ? wk : wv);
        dst = wb + (long)w * 262144;
    }
    float4 f = ((const float4*)src)[off];
    ushort4 o;
    o.x = f2bf(f.x); o.y = f2bf(f.y); o.z = f2bf(f.z); o.w = f2bf(f.w);
    ((ushort4*)dst)[off] = o;
}

// ---------------- QKV projection: 64x64 tile, BK=64, reg double-buffer (R5 winner) ----------------
// C[m,n] = sum_k X[m,k] W[n,k] + bias[n].  Outputs bf16, coalesced via LDS transpose.
// z==0 -> q[m][n], z==1 -> k[m][n], z==2 -> vT[n][m] (token-contiguous rows).
// grid (64,8,3) = 1536 blocks = 6 blocks/CU.
#define ALD 72   // LDS row stride (bf16): 36 dw -> 2-way conflicts only per 16-lane phase
__global__ __launch_bounds__(256) void qkv_gemm(
    const unsigned short* __restrict__ xb,   // 4096 x 512
    const unsigned short* __restrict__ wb,   // 3 x (512 x 512), (N,K)
    const float* __restrict__ bq, const float* __restrict__ bk, const float* __restrict__ bv,
    unsigned short* __restrict__ q, unsigned short* __restrict__ k,
    unsigned short* __restrict__ vt)
{
    __shared__ __align__(16) unsigned short As[64 * ALD];   // 9216 B (aliased by epilogue)
    __shared__ __align__(16) unsigned short Bs[64 * ALD];

    const int t = threadIdx.x;
    const int w = t >> 6, l = t & 63;
    const int m0 = blockIdx.x * 64, n0 = blockIdx.y * 64, z = blockIdx.z;
    const unsigned short* W = wb + (size_t)z * 262144;
    const float* bias = (z == 0) ? bq : ((z == 1) ? bk : bv);

    floatx4 acc[2][2] = {};
    const int wm = (w >> 1) * 32, wn = (w & 1) * 32;
    const int fr = l & 15, fq = l >> 4, fk = fq * 8;

    const int srow = t >> 2, scol = (t & 3) * 16;
    const unsigned short* gA = xb + (size_t)(m0 + srow) * 512 + scol;
    const unsigned short* gB = W  + (size_t)(n0 + srow) * 512 + scol;

    uint4 ra0 = *(const uint4*)(gA);     uint4 ra1 = *(const uint4*)(gA + 8);
    uint4 rb0 = *(const uint4*)(gB);     uint4 rb1 = *(const uint4*)(gB + 8);

    for (int it = 0; it < 8; it++) {
        *(uint4*)&As[srow * ALD + scol]     = ra0;
        *(uint4*)&As[srow * ALD + scol + 8] = ra1;
        *(uint4*)&Bs[srow * ALD + scol]     = rb0;
        *(uint4*)&Bs[srow * ALD + scol + 8] = rb1;
        __syncthreads();
        if (it < 7) {                       // prefetch next K-slice; overlaps compute below
            int kk = (it + 1) * 64;
            ra0 = *(const uint4*)(gA + kk); ra1 = *(const uint4*)(gA + kk + 8);
            rb0 = *(const uint4*)(gB + kk); rb1 = *(const uint4*)(gB + kk + 8);
        }
        short8 a[2][2], bf[2][2];
#pragma unroll
        for (int i = 0; i < 2; i++)
#pragma unroll
            for (int kh = 0; kh < 2; kh++)
                a[i][kh] = *(const short8*)&As[(wm + i * 16 + fr) * ALD + kh * 32 + fk];
#pragma unroll
        for (int j = 0; j < 2; j++)
#pragma unroll
            for (int kh = 0; kh < 2; kh++)
                bf[j][kh] = *(const short8*)&Bs[(wn + j * 16 + fr) * ALD + kh * 32 + fk];
#pragma unroll
        for (int kh = 0; kh < 2; kh++)
#pragma unroll
            for (int i = 0; i < 2; i++)
#pragma unroll
                for (int j = 0; j < 2; j++)
                    acc[i][j] = __builtin_amdgcn_mfma_f32_16x16x32_bf16(a[i][kh], bf[j][kh], acc[i][j], 0, 0, 0);
        __syncthreads();
    }

    // epilogue: frags (C/D: col=lane&15, row=(lane>>4)*4+reg) -> LDS tile -> coalesced stores
    unsigned short* Tl = As;   // 64 x ALD alias
    float bv_[2];
#pragma unroll
    for (int j = 0; j < 2; j++) bv_[j] = bias[n0 + wn + j * 16 + fr];

    if (z < 2) {
#pragma unroll
        for (int i = 0; i < 2; i++)
#pragma unroll
            for (int j = 0; j < 2; j++)
#pragma unroll
                for (int r = 0; r < 4; r++)
                    Tl[(wm + i * 16 + fq * 4 + r) * ALD + wn + j * 16 + fr] =
                        f2bf(acc[i][j][r] + bv_[j]);
    } else {
#pragma unroll
        for (int i = 0; i < 2; i++)
#pragma unroll
            for (int j = 0; j < 2; j++)
#pragma unroll
                for (int r = 0; r < 4; r++)
                    Tl[(wn + j * 16 + fr) * ALD + wm + i * 16 + fq * 4 + r] =
                        f2bf(acc[i][j][r] + bv_[j]);
    }
    __syncthreads();

    const int tr = t >> 2, tc = (t & 3) * 16;
    uint4 v0 = *(const uint4*)&Tl[tr * ALD + tc];
    uint4 v1 = *(const uint4*)&Tl[tr * ALD + tc + 8];
    if (z < 2) {
        unsigned short* out = (z == 0) ? q : k;
        *(uint4*)&out[(size_t)(m0 + tr) * 512 + n0 + tc]     = v0;
        *(uint4*)&out[(size_t)(m0 + tr) * 512 + n0 + tc + 8] = v1;
    } else {
        *(uint4*)&vt[(size_t)(n0 + tr) * 4096 + m0 + tc]     = v0;
        *(uint4*)&vt[(size_t)(n0 + tr) * 4096 + m0 + tc + 8] = v1;
    }
}

// ---------------- fused attention: 8 waves per 16-row Q-tile ----------------
// grid (128 Qtiles, 2 b), 512 threads. Wave w computes score n-tile w (wave 0
// also tile 8) into a shared fp32 LDS S-tile; one barrier; every wave
// redundantly computes the row-softmax from LDS (pure function, cheaper than a
// second barrier + P round-trip) and builds bf16 A-frags in-register; wave w
// then runs PV for E-cols [64w, 64w+64).  256 blocks = 1 block/CU but 8
// waves/CU (2/SIMD): the serial chain per wave is ~8x shorter than the 1-wave
// version and loads from different waves overlap.
#define SLD 164   // LDS row stride (fp32): 164%32=4 -> 2-way conflicts max on row reads
__global__ __launch_bounds__(512) void attn_fused(
    const unsigned short* __restrict__ qb, const unsigned short* __restrict__ kb,
    const unsigned short* __restrict__ vt, float* __restrict__ out)
{
    __shared__ __align__(16) float Sl[16 * SLD];   // 10.5 KB

    const int t = threadIdx.x;
    const int w = t >> 6, l = t & 63;
    const int fr = l & 15, fq = l >> 4;
    const int Q0 = blockIdx.x * 16;
    const int b  = blockIdx.y;
    const int R0 = Q0 - WIN;

    // ---- scores: wave w handles n-tile(s) {w, w+8} (only wave 0 gets a second)
    {
        const unsigned short* qrow = qb + (size_t)(b * L_SEQ + Q0 + fr) * 512 + fq * 8;
        short8 qf[16];
#pragma unroll
        for (int ks = 0; ks < 16; ks++) qf[ks] = *(const short8*)(qrow + ks * 32);

        for (int nt = w; nt < 9; nt += 8) {
            const int tok = R0 + nt * 16 + fr;
            const bool kvalid = (tok >= 0) && (tok < L_SEQ);
            const unsigned short* krow = kb + (size_t)(b * L_SEQ) * 512 + (size_t)tok * 512 + fq * 8;

            floatx4 acc = {};
#pragma unroll
            for (int ks = 0; ks < 16; ks++) {
                short8 bfr = {};
                if (kvalid) bfr = *(const short8*)(krow + ks * 32);
                acc = __builtin_amdgcn_mfma_f32_16x16x32_bf16(qf[ks], bfr, acc, 0, 0, 0);
            }
            const int jg = nt * 16 + fr;
#pragma unroll
            for (int r = 0; r < 4; r++) {
                int qq = fq * 4 + r;    // C/D layout: col=lane&15, row=(lane>>4)*4+r
                bool valid = kvalid && (jg >= qq) && (jg <= qq + 128);
                Sl[qq * SLD + jg] = valid ? acc[r] * SCALE_QK : -1e30f;
            }
        }
    }
    __syncthreads();

    // ---- softmax (per-wave redundant): lane covers row fr, cols fq*8 + ks*32 + j
    const float* Srow = &Sl[fr * SLD + fq * 8];
    float sv[5][8];
#pragma unroll
    for (int ks = 0; ks < 5; ks++) {
        float4 u0 = *(const float4*)(Srow + ks * 32);
        float4 u1 = *(const float4*)(Srow + ks * 32 + 4);
        sv[ks][0] = u0.x; sv[ks][1] = u0.y; sv[ks][2] = u0.z; sv[ks][3] = u0.w;
        sv[ks][4] = u1.x; sv[ks][5] = u1.y; sv[ks][6] = u1.z; sv[ks][7] = u1.w;
    }
    if (fq >= 2) {                    // cols 144..159: unwritten pad
#pragma unroll
        for (int j = 0; j < 8; j++) sv[4][j] = -1e30f;
    }
    float m = -1e30f;
#pragma unroll
    for (int ks = 0; ks < 5; ks++)
#pragma unroll
        for (int j = 0; j < 8; j++) m = fmaxf(m, sv[ks][j]);
    m = fmaxf(m, __shfl_xor(m, 16));
    m = fmaxf(m, __shfl_xor(m, 32));
    float sum = 0.f;
#pragma unroll
    for (int ks = 0; ks < 5; ks++)
#pragma unroll
        for (int j = 0; j < 8; j++) { float e = __expf(sv[ks][j] - m); sv[ks][j] = e; sum += e; }
    sum += __shfl_xor(sum, 16);
    sum += __shfl_xor(sum, 32);
    float inv = 1.f / sum;

    short8 a[5];     // P in A-frag layout: row fr, k-pos fq*8+j within 32-slice ks
#pragma unroll
    for (int ks = 0; ks < 5; ks++)
#pragma unroll
        for (int j = 0; j < 8; j++) a[ks][j] = (short)f2bf(sv[ks][j] * inv);

    // ---- PV: wave w owns E-cols [64w, 64w+64)
    const int EC = w * 64;
    floatx4 oa[4] = {};
#pragma unroll
    for (int ks = 0; ks < 5; ks++) {
        int tok0 = R0 + ks * 32 + fq * 8;              // mod-8 aligned granule
        bool tv = (tok0 >= 0) && (tok0 < L_SEQ);
#pragma unroll
        for (int et = 0; et < 4; et++) {
            short8 bfr = {};
            if (tv) bfr = *(const short8*)&vt[(size_t)(EC + et * 16 + fr) * 4096 + b * L_SEQ + tok0];
            oa[et] = __builtin_amdgcn_mfma_f32_16x16x32_bf16(a[ks], bfr, oa[et], 0, 0, 0);
        }
    }

    float* op = out + (size_t)b * L_SEQ * E_DIM;
#pragma unroll
    for (int et = 0; et < 4; et++)
#pragma unroll
        for (int r = 0; r < 4; r++)
            op[(size_t)(Q0 + fq * 4 + r) * 512 + EC + et * 16 + fr] = oa[et][r];
}

// ---------------- launch ----------------
extern "C" void kernel_launch(void* const* d_in, const int* in_sizes, int n_in,
                              void* d_out, int out_size, void* d_ws, size_t ws_size,
                              hipStream_t stream)
{
    const float* x  = (const float*)d_in[0];
    const float* Wq = (const float*)d_in[1];
    const float* bq = (const float*)d_in[2];
    const float* Wk = (const float*)d_in[3];
    const float* bk = (const float*)d_in[4];
    const float* Wv = (const float*)d_in[5];
    const float* bv = (const float*)d_in[6];
    float* out = (float*)d_out;

    char* ws = (char*)d_ws;
    unsigned short* qb = (unsigned short*)(ws);                  // 4 MB bf16 q
    unsigned short* kb = (unsigned short*)(ws + 4194304);        // 4 MB bf16 k
    unsigned short* vt = (unsigned short*)(ws + 8388608);        // 4 MB bf16 v^T [e][tok]
    unsigned short* xb = (unsigned short*)(ws + 12582912);       // 4 MB bf16 x
    unsigned short* wb = (unsigned short*)(ws + 16777216);       // 1.5 MB bf16 W

    cvt_kernel<<<2816, 256, 0, stream>>>(x, Wq, Wk, Wv, xb, wb);
    qkv_gemm<<<dim3(64, 8, 3), 256, 0, stream>>>(xb, wb, bq, bk, bv, qb, kb, vt);
    attn_fused<<<dim3(128, 2), 512, 0, stream>>>(qb, kb, vt, out);
}

// Round 3
// 106.181 us; speedup vs baseline: 1.5224x; 1.0599x over previous
//
#include <hip/hip_runtime.h>
#include <cstdint>
#include <cstddef>

#define L_SEQ 2048
#define E_DIM 512
#define B_SZ 2
#define WIN 64
#define SCALE_QK 0.044194173824159216f  // 1/sqrt(512)

typedef __attribute__((ext_vector_type(8))) short short8;
typedef __attribute__((ext_vector_type(4))) float floatx4;

__device__ __forceinline__ unsigned short f2bf(float f) {
    unsigned int u = __float_as_uint(f);
    u += 0x7FFFu + ((u >> 16) & 1u);
    return (unsigned short)(u >> 16);
}

// ---------------- fp32 -> bf16 conversion of x, Wq, Wk, Wv ----------------
__global__ __launch_bounds__(256) void cvt_kernel(
    const float* __restrict__ x, const float* __restrict__ wq,
    const float* __restrict__ wk, const float* __restrict__ wv,
    unsigned short* __restrict__ xb, unsigned short* __restrict__ wb)
{
    long i = (long)blockIdx.x * 256 + threadIdx.x;   // 0 .. 720895
    const float* src;
    unsigned short* dst;
    long off;
    if (i < 524288) {
        src = x; dst = xb; off = i;
    } else {
        long j = i - 524288;
        int w = (int)(j >> 16);
        off = j & 65535;
        src = (w == 0) ? wq : ((w == 1) ? wk : wv);
        dst = wb + (long)w * 262144;
    }
    float4 f = ((const float4*)src)[off];
    ushort4 o;
    o.x = f2bf(f.x); o.y = f2bf(f.y); o.z = f2bf(f.z); o.w = f2bf(f.w);
    ((ushort4*)dst)[off] = o;
}

// ---------------- QKV projection: 64x64 tile, BK=64, reg double-buffer (R5 winner) ----------------
// C[m,n] = sum_k X[m,k] W[n,k] + bias[n].  Outputs bf16, coalesced via LDS transpose.
// z==0 -> q[m][n], z==1 -> k[m][n], z==2 -> vT[n][m] (token-contiguous rows).
// grid (64,8,3) = 1536 blocks = 6 blocks/CU.
#define ALD 72   // LDS row stride (bf16): 36 dw -> 2-way conflicts only per 16-lane phase
__global__ __launch_bounds__(256) void qkv_gemm(
    const unsigned short* __restrict__ xb,   // 4096 x 512
    const unsigned short* __restrict__ wb,   // 3 x (512 x 512), (N,K)
    const float* __restrict__ bq, const float* __restrict__ bk, const float* __restrict__ bv,
    unsigned short* __restrict__ q, unsigned short* __restrict__ k,
    unsigned short* __restrict__ vt)
{
    __shared__ __align__(16) unsigned short As[64 * ALD];   // 9216 B (aliased by epilogue)
    __shared__ __align__(16) unsigned short Bs[64 * ALD];

    const int t = threadIdx.x;
    const int w = t >> 6, l = t & 63;
    const int m0 = blockIdx.x * 64, n0 = blockIdx.y * 64, z = blockIdx.z;
    const unsigned short* W = wb + (size_t)z * 262144;
    const float* bias = (z == 0) ? bq : ((z == 1) ? bk : bv);

    floatx4 acc[2][2] = {};
    const int wm = (w >> 1) * 32, wn = (w & 1) * 32;
    const int fr = l & 15, fq = l >> 4, fk = fq * 8;

    const int srow = t >> 2, scol = (t & 3) * 16;
    const unsigned short* gA = xb + (size_t)(m0 + srow) * 512 + scol;
    const unsigned short* gB = W  + (size_t)(n0 + srow) * 512 + scol;

    uint4 ra0 = *(const uint4*)(gA);     uint4 ra1 = *(const uint4*)(gA + 8);
    uint4 rb0 = *(const uint4*)(gB);     uint4 rb1 = *(const uint4*)(gB + 8);

    for (int it = 0; it < 8; it++) {
        *(uint4*)&As[srow * ALD + scol]     = ra0;
        *(uint4*)&As[srow * ALD + scol + 8] = ra1;
        *(uint4*)&Bs[srow * ALD + scol]     = rb0;
        *(uint4*)&Bs[srow * ALD + scol + 8] = rb1;
        __syncthreads();
        if (it < 7) {                       // prefetch next K-slice; overlaps compute below
            int kk = (it + 1) * 64;
            ra0 = *(const uint4*)(gA + kk); ra1 = *(const uint4*)(gA + kk + 8);
            rb0 = *(const uint4*)(gB + kk); rb1 = *(const uint4*)(gB + kk + 8);
        }
        short8 a[2][2], bf[2][2];
#pragma unroll
        for (int i = 0; i < 2; i++)
#pragma unroll
            for (int kh = 0; kh < 2; kh++)
                a[i][kh] = *(const short8*)&As[(wm + i * 16 + fr) * ALD + kh * 32 + fk];
#pragma unroll
        for (int j = 0; j < 2; j++)
#pragma unroll
            for (int kh = 0; kh < 2; kh++)
                bf[j][kh] = *(const short8*)&Bs[(wn + j * 16 + fr) * ALD + kh * 32 + fk];
#pragma unroll
        for (int kh = 0; kh < 2; kh++)
#pragma unroll
            for (int i = 0; i < 2; i++)
#pragma unroll
                for (int j = 0; j < 2; j++)
                    acc[i][j] = __builtin_amdgcn_mfma_f32_16x16x32_bf16(a[i][kh], bf[j][kh], acc[i][j], 0, 0, 0);
        __syncthreads();
    }

    // epilogue: frags (C/D: col=lane&15, row=(lane>>4)*4+reg) -> LDS tile -> coalesced stores
    unsigned short* Tl = As;   // 64 x ALD alias
    float bv_[2];
#pragma unroll
    for (int j = 0; j < 2; j++) bv_[j] = bias[n0 + wn + j * 16 + fr];

    if (z < 2) {
#pragma unroll
        for (int i = 0; i < 2; i++)
#pragma unroll
            for (int j = 0; j < 2; j++)
#pragma unroll
                for (int r = 0; r < 4; r++)
                    Tl[(wm + i * 16 + fq * 4 + r) * ALD + wn + j * 16 + fr] =
                        f2bf(acc[i][j][r] + bv_[j]);
    } else {
#pragma unroll
        for (int i = 0; i < 2; i++)
#pragma unroll
            for (int j = 0; j < 2; j++)
#pragma unroll
                for (int r = 0; r < 4; r++)
                    Tl[(wn + j * 16 + fr) * ALD + wm + i * 16 + fq * 4 + r] =
                        f2bf(acc[i][j][r] + bv_[j]);
    }
    __syncthreads();

    const int tr = t >> 2, tc = (t & 3) * 16;
    uint4 v0 = *(const uint4*)&Tl[tr * ALD + tc];
    uint4 v1 = *(const uint4*)&Tl[tr * ALD + tc + 8];
    if (z < 2) {
        unsigned short* out = (z == 0) ? q : k;
        *(uint4*)&out[(size_t)(m0 + tr) * 512 + n0 + tc]     = v0;
        *(uint4*)&out[(size_t)(m0 + tr) * 512 + n0 + tc + 8] = v1;
    } else {
        *(uint4*)&vt[(size_t)(n0 + tr) * 4096 + m0 + tc]     = v0;
        *(uint4*)&vt[(size_t)(n0 + tr) * 4096 + m0 + tc + 8] = v1;
    }
}

// ---------------- fused attention: 8 waves per 16-row Q-tile ----------------
// grid (128 Qtiles, 2 b), 512 threads. Wave w computes score n-tile w (wave 0
// also tile 8) into a shared fp32 LDS S-tile; one barrier; every wave
// redundantly computes the row-softmax from LDS; wave w runs PV for E-cols
// [64w, 64w+64).
// KEY (this round): all global loads are UNCONDITIONAL with clamped addresses
// and batched into register groups before the MFMA chains.  Masking is done
// entirely on values (-1e30 into S for invalid cols -> P=0 -> 0*V=0), so the
// compiler can issue 8 (K) / 5 (V) loads back-to-back under one vmcnt wait
// instead of one exposed ~600-cycle latency per load behind a divergent branch.
#define SLD 164   // LDS row stride (fp32): 164%32=4 -> 2-way conflicts max on row reads
__global__ __launch_bounds__(512) void attn_fused(
    const unsigned short* __restrict__ qb, const unsigned short* __restrict__ kb,
    const unsigned short* __restrict__ vt, float* __restrict__ out)
{
    __shared__ __align__(16) float Sl[16 * SLD];   // 10.5 KB

    const int t = threadIdx.x;
    const int w = t >> 6, l = t & 63;
    const int fr = l & 15, fq = l >> 4;
    const int Q0 = blockIdx.x * 16;
    const int b  = blockIdx.y;
    const int R0 = Q0 - WIN;

    // ---- scores: wave w handles n-tile(s) {w, w+8} (only wave 0 gets a second)
    {
        const unsigned short* qrow = qb + (size_t)(b * L_SEQ + Q0 + fr) * 512 + fq * 8;
        short8 qf[16];
#pragma unroll
        for (int ks = 0; ks < 16; ks++) qf[ks] = *(const short8*)(qrow + ks * 32);

        for (int nt = w; nt < 9; nt += 8) {
            const int tok = R0 + nt * 16 + fr;
            const bool kvalid = (tok >= 0) && (tok < L_SEQ);
            const int tokc = min(max(tok, 0), L_SEQ - 1);        // clamped: always a real row
            const unsigned short* krow = kb + (size_t)(b * L_SEQ + tokc) * 512 + fq * 8;

            floatx4 acc0 = {}, acc1 = {};                        // 2 chains (8-deep, not 16)
            short8 bfr[8];
#pragma unroll
            for (int ks = 0; ks < 8; ks++) bfr[ks] = *(const short8*)(krow + ks * 32);
#pragma unroll
            for (int ks = 0; ks < 8; ks++)
                acc0 = __builtin_amdgcn_mfma_f32_16x16x32_bf16(qf[ks], bfr[ks], acc0, 0, 0, 0);
#pragma unroll
            for (int ks = 0; ks < 8; ks++) bfr[ks] = *(const short8*)(krow + (8 + ks) * 32);
#pragma unroll
            for (int ks = 0; ks < 8; ks++)
                acc1 = __builtin_amdgcn_mfma_f32_16x16x32_bf16(qf[8 + ks], bfr[ks], acc1, 0, 0, 0);

            const int jg = nt * 16 + fr;
#pragma unroll
            for (int r = 0; r < 4; r++) {
                int qq = fq * 4 + r;    // C/D layout: col=lane&15, row=(lane>>4)*4+r
                bool valid = kvalid && (jg >= qq) && (jg <= qq + 128);
                Sl[qq * SLD + jg] = valid ? (acc0[r] + acc1[r]) * SCALE_QK : -1e30f;
            }
        }
    }
    __syncthreads();

    // ---- softmax (per-wave redundant): lane covers row fr, cols fq*8 + ks*32 + j
    const float* Srow = &Sl[fr * SLD + fq * 8];
    float sv[5][8];
#pragma unroll
    for (int ks = 0; ks < 5; ks++) {
        float4 u0 = *(const float4*)(Srow + ks * 32);
        float4 u1 = *(const float4*)(Srow + ks * 32 + 4);
        sv[ks][0] = u0.x; sv[ks][1] = u0.y; sv[ks][2] = u0.z; sv[ks][3] = u0.w;
        sv[ks][4] = u1.x; sv[ks][5] = u1.y; sv[ks][6] = u1.z; sv[ks][7] = u1.w;
    }
    if (fq >= 2) {                    // cols 144..159: unwritten pad
#pragma unroll
        for (int j = 0; j < 8; j++) sv[4][j] = -1e30f;
    }
    float m = -1e30f;
#pragma unroll
    for (int ks = 0; ks < 5; ks++)
#pragma unroll
        for (int j = 0; j < 8; j++) m = fmaxf(m, sv[ks][j]);
    m = fmaxf(m, __shfl_xor(m, 16));
    m = fmaxf(m, __shfl_xor(m, 32));
    float sum = 0.f;
#pragma unroll
    for (int ks = 0; ks < 5; ks++)
#pragma unroll
        for (int j = 0; j < 8; j++) { float e = __expf(sv[ks][j] - m); sv[ks][j] = e; sum += e; }
    sum += __shfl_xor(sum, 16);
    sum += __shfl_xor(sum, 32);
    float inv = 1.f / sum;

    short8 a[5];     // P in A-frag layout: row fr, k-pos fq*8+j within 32-slice ks
#pragma unroll
    for (int ks = 0; ks < 5; ks++)
#pragma unroll
        for (int j = 0; j < 8; j++) a[ks][j] = (short)f2bf(sv[ks][j] * inv);

    // ---- PV: wave w owns E-cols [64w, 64w+64); loads clamped + batched (P=0 masks OOB)
    const int EC = w * 64;
    int tkc[5];
#pragma unroll
    for (int ks = 0; ks < 5; ks++) {
        int tok0 = R0 + ks * 32 + fq * 8;              // mod-8 aligned granule
        tkc[ks] = min(max(tok0, 0), L_SEQ - 8);        // clamp keeps 16B alignment
    }
    floatx4 oa[4] = {};
#pragma unroll
    for (int et = 0; et < 4; et++) {
        const unsigned short* vrow = vt + (size_t)(EC + et * 16 + fr) * 4096 + b * L_SEQ;
        short8 vfr[5];
#pragma unroll
        for (int ks = 0; ks < 5; ks++) vfr[ks] = *(const short8*)(vrow + tkc[ks]);
#pragma unroll
        for (int ks = 0; ks < 5; ks++)
            oa[et] = __builtin_amdgcn_mfma_f32_16x16x32_bf16(a[ks], vfr[ks], oa[et], 0, 0, 0);
    }

    float* op = out + (size_t)b * L_SEQ * E_DIM;
#pragma unroll
    for (int et = 0; et < 4; et++)
#pragma unroll
        for (int r = 0; r < 4; r++)
            op[(size_t)(Q0 + fq * 4 + r) * 512 + EC + et * 16 + fr] = oa[et][r];
}

// ---------------- launch ----------------
extern "C" void kernel_launch(void* const* d_in, const int* in_sizes, int n_in,
                              void* d_out, int out_size, void* d_ws, size_t ws_size,
                              hipStream_t stream)
{
    const float* x  = (const float*)d_in[0];
    const float* Wq = (const float*)d_in[1];
    const float* bq = (const float*)d_in[2];
    const float* Wk = (const float*)d_in[3];
    const float* bk = (const float*)d_in[4];
    const float* Wv = (const float*)d_in[5];
    const float* bv = (const float*)d_in[6];
    float* out = (float*)d_out;

    char* ws = (char*)d_ws;
    unsigned short* qb = (unsigned short*)(ws);                  // 4 MB bf16 q
    unsigned short* kb = (unsigned short*)(ws + 4194304);        // 4 MB bf16 k
    unsigned short* vt = (unsigned short*)(ws + 8388608);        // 4 MB bf16 v^T [e][tok]
    unsigned short* xb = (unsigned short*)(ws + 12582912);       // 4 MB bf16 x
    unsigned short* wb = (unsigned short*)(ws + 16777216);       // 1.5 MB bf16 W

    cvt_kernel<<<2816, 256, 0, stream>>>(x, Wq, Wk, Wv, xb, wb);
    qkv_gemm<<<dim3(64, 8, 3), 256, 0, stream>>>(xb, wb, bq, bk, bv, qb, kb, vt);
    attn_fused<<<dim3(128, 2), 512, 0, stream>>>(qb, kb, vt, out);
}